// Round 3
// baseline (7977.557 us; speedup 1.0000x reference)
//
#include <hip/hip_runtime.h>
#include <hip/hip_bf16.h>

// Problem constants
#define HEADS  8
#define BATCH  32
#define SLEN   325
#define LSTEPS 192
#define DM     128
#define NSEQ   (BATCH*SLEN)          // 10400
#define LOG2E  1.4426950408889634f

typedef _Float16 half8  __attribute__((ext_vector_type(8)));
typedef _Float16 half4t __attribute__((ext_vector_type(4)));
typedef float    floatx4 __attribute__((ext_vector_type(4)));
typedef float    float2v __attribute__((ext_vector_type(2)));

__device__ __forceinline__ float fexp2(float x) { return __builtin_amdgcn_exp2f(x); }
__device__ __forceinline__ float frcp(float x)  { return __builtin_amdgcn_rcpf(x); }
// z' = -log2e * z  ->  sigmoid(z)
__device__ __forceinline__ float sigm_pre(float zs) { return frcp(1.f + fexp2(zs)); }
// z' = 2*log2e * z ->  tanh(z)
__device__ __forceinline__ float tanh_pre(float zs) { return 1.f - 2.f*frcp(1.f + fexp2(zs)); }

// ---------------------------------------------------------------------------
// Kernel 1: v-LSTM (hidden size 1), one thread per (head, sequence).
// ---------------------------------------------------------------------------
__global__ void v_lstm_kernel(const float* __restrict__ x,
                              const float* __restrict__ vWih,
                              const float* __restrict__ vWhh,
                              const float* __restrict__ vbih,
                              const float* __restrict__ vbhh,
                              float* __restrict__ v_buf) {
  int gid = blockIdx.x * 256 + threadIdx.x;
  if (gid >= HEADS * NSEQ) return;
  int hh = gid / NSEQ;
  int n  = gid - hh * NSEQ;

  float wih[4], whh[4], bb[4];
#pragma unroll
  for (int g = 0; g < 4; ++g) {
    float sc = (g == 2) ? 2.f*LOG2E : -LOG2E;
    wih[g] = vWih[hh*4+g] * sc;
    whh[g] = vWhh[hh*4+g] * sc;
    bb[g]  = (vbih[hh*4+g] + vbhh[hh*4+g]) * sc;
  }
  const float* xr = x + (size_t)n * LSTEPS;
  float* vo = v_buf + (size_t)hh * LSTEPS * NSEQ + n;
  float hpr = 0.f, c = 0.f;
  for (int t = 0; t < LSTEPS; ++t) {
    float xt = xr[t];
    float zi = fmaf(wih[0], xt, fmaf(whh[0], hpr, bb[0]));
    float zf = fmaf(wih[1], xt, fmaf(whh[1], hpr, bb[1]));
    float zg = fmaf(wih[2], xt, fmaf(whh[2], hpr, bb[2]));
    float zo = fmaf(wih[3], xt, fmaf(whh[3], hpr, bb[3]));
    float si = sigm_pre(zi), sf = sigm_pre(zf), so = sigm_pre(zo);
    float tg = tanh_pre(zg);
    c = fmaf(sf, c, si * tg);
    float tc = tanh_pre(2.f*LOG2E*c);
    hpr = so * tc;
    vo[(size_t)t * NSEQ] = hpr;
  }
}

// ---------------------------------------------------------------------------
// Kernel 2: q/k LSTMs via fp16 MFMA.
//
// R9 (packed-f32 gate math): R8 proved occupancy is NOT the limiter
// (2 blocks/CU, Occ 22->45%, dur unchanged 7.5ms; VALU 58->60.6 only).
// Time tracks the invariant per-CU math work. SQ_LDS_BANK_CONFLICT is
// byte-identical (2.87e8) across R6/R7/R8 including R7's provably
// conflict-free write swizzle -> that counter is the STRUCTURAL cost of
// wave64 ds_read_b128 (~12cyc vs 8 ideal, m134), not fixable -> don't
// chase it. Attack: per-cell VALU issue count. Gate math rewritten over
// float2 cell-pairs + float4 acc-init so the backend emits double-rate
// v_pk_{fma,add,mul}_f32 (CDNA 2x-rate packed f32). clamp min(carg,126)
// replaced by equivalent fmaxf(cc,-43.668) pre-clamp (same NaN guard).
// Exact f32 arithmetic unchanged.
//
// R8 structure kept: Mt=2, 2 blocks/CU via __launch_bounds__(512,4),
// gate-0 weights streamed from LDS (w0_lds) so bfrag=48 regs and the
// 128-reg cap does NOT spill (R7 lesson: cap below structural demand ->
// bfrag to scratch -> GBs of HBM). Watch FETCH/WRITE for spill regression.
// ---------------------------------------------------------------------------
__global__ __launch_bounds__(512, 4)
void qk_lstm_kernel(const float* __restrict__ qWih, const float* __restrict__ qWhh,
                    const float* __restrict__ qbih, const float* __restrict__ qbhh,
                    const float* __restrict__ kWih, const float* __restrict__ kWhh,
                    const float* __restrict__ kbih, const float* __restrict__ kbhh,
                    const float* __restrict__ x,
                    _Float16* __restrict__ q_buf, _Float16* __restrict__ k_buf) {
  __shared__ _Float16 x_lds[LSTEPS * 32];        // [t][n_local], fp16, 12.0 KB
  __shared__ _Float16 h_lds[2][32 * 136];        // [buf][row][kk], pad 136, 17.0 KB
  __shared__ half8    w0_lds[8 * 4 * 64];        // [wave][kc][lane] gate-0 B frags, 32 KB

  const int lsi = blockIdx.x / 325;              // 0..15 : q heads 0-7 then k heads 0-7
  const int n0  = (blockIdx.x % 325) * 32;       // exact: 325*32 = 10400 = NSEQ
  const int head = lsi & 7;
  const bool isq = lsi < 8;
  const float* Wih = (isq ? qWih : kWih) + head * 512;
  const float* Whh = (isq ? qWhh : kWhh) + (size_t)head * 512 * 128;
  const float* bih = (isq ? qbih : kbih) + head * 512;
  const float* bhh = (isq ? qbhh : kbhh) + head * 512;

  const int tid  = threadIdx.x;
  const int w    = tid >> 6;       // wave 0..7
  const int lane = tid & 63;
  const int l16  = lane & 15;
  const int quad = lane >> 4;      // 0..3
  const int kw   = w * 16;         // wave's kk slice base

  // --- load W^T fragments (pre-scaled); gate 0 -> LDS, gates 1..3 -> regs ---
  half8 bfrag[3][4];               // [gate-1][kchunk] = 48 VGPRs
  float wih_s[4], b_s[4];
#pragma unroll
  for (int g = 0; g < 4; ++g) {
    const float sc = (g == 2) ? 2.f*LOG2E : -LOG2E;
    const int col = g * 128 + kw + l16;          // global z column
    wih_s[g] = Wih[col] * sc;
    b_s[g]   = (bih[col] + bhh[col]) * sc;
#pragma unroll
    for (int kc = 0; kc < 4; ++kc) {
      const int k0 = kc * 32 + quad * 8;
      const float4 v0 = *(const float4*)&Whh[(size_t)col * 128 + k0];
      const float4 v1 = *(const float4*)&Whh[(size_t)col * 128 + k0 + 4];
      half8 f;
      f[0] = (_Float16)(v0.x * sc); f[1] = (_Float16)(v0.y * sc);
      f[2] = (_Float16)(v0.z * sc); f[3] = (_Float16)(v0.w * sc);
      f[4] = (_Float16)(v1.x * sc); f[5] = (_Float16)(v1.y * sc);
      f[6] = (_Float16)(v1.z * sc); f[7] = (_Float16)(v1.w * sc);
      if (g == 0) w0_lds[(w * 4 + kc) * 64 + lane] = f;   // lane-linear, 16B/lane
      else        bfrag[g - 1][kc] = f;
    }
  }

  // --- stage x transposed into LDS (full 192 steps), coalesced float4 ---
  for (int u = tid; u < 32 * 48; u += 512) {
    const int rr = u / 48, tq = u - rr * 48;     // tq: group of 4 steps
    const int n = n0 + rr;                       // always < NSEQ (exact tiling)
    const float4 xv = *(const float4*)&x[(size_t)n * LSTEPS + tq * 4];
    x_lds[(tq * 4 + 0) * 32 + rr] = (_Float16)xv.x;
    x_lds[(tq * 4 + 1) * 32 + rr] = (_Float16)xv.y;
    x_lds[(tq * 4 + 2) * 32 + rr] = (_Float16)xv.z;
    x_lds[(tq * 4 + 3) * 32 + rr] = (_Float16)xv.w;
  }
  for (int idx = tid; idx < 32 * 136; idx += 512) h_lds[0][idx] = (_Float16)0.f;
  __syncthreads();

  floatx4 acc[2][4];               // [Mtile][gate] -> 32 accum regs
  float c[8];
#pragma unroll
  for (int i = 0; i < 8; ++i) c[i] = 0.f;

  for (int t = 0; t < LSTEPS; ++t) {
    const int pb = t & 1;
    // acc init: z0 = b' + wih'*x_t (vector form -> v_pk_fma_f32 pairs)
#pragma unroll
    for (int Mt = 0; Mt < 2; ++Mt) {
      const half4t xq = *(const half4t*)&x_lds[t * 32 + Mt * 16 + quad * 4];
      floatx4 xv4;
      xv4[0] = (float)xq[0]; xv4[1] = (float)xq[1];
      xv4[2] = (float)xq[2]; xv4[3] = (float)xq[3];
#pragma unroll
      for (int g = 0; g < 4; ++g)
        acc[Mt][g] = xv4 * wih_s[g] + b_s[g];
    }
    // MFMA: z += h @ W^T ; gate 0's B frag streamed from LDS per kc
#pragma unroll
    for (int kc = 0; kc < 4; ++kc) {
      const half8 b0 = w0_lds[(w * 4 + kc) * 64 + lane];
#pragma unroll
      for (int Mt = 0; Mt < 2; ++Mt) {
        const half8 af = *(const half8*)&h_lds[pb][(Mt * 16 + l16) * 136 + kc * 32 + quad * 8];
        acc[Mt][0] = __builtin_amdgcn_mfma_f32_16x16x32_f16(af, b0, acc[Mt][0], 0, 0, 0);
#pragma unroll
        for (int g = 1; g < 4; ++g)
          acc[Mt][g] = __builtin_amdgcn_mfma_f32_16x16x32_f16(af, bfrag[g - 1][kc], acc[Mt][g], 0, 0, 0);
      }
    }
    // Packed-f32 gate math over row pairs (2p, 2p+1). Same algebra as R5's
    // 7-trans form: acc0=-zi*l2e, acc1=-zf*l2e, acc2=+2zg*l2e, acc3=-zo*l2e.
#pragma unroll
    for (int Mt = 0; Mt < 2; ++Mt) {
#pragma unroll
      for (int p = 0; p < 2; ++p) {
        const int r0 = 2 * p, r1 = 2 * p + 1;
        const int ci = Mt * 4 + r0;
        float2v Ei = { fexp2(acc[Mt][0][r0]), fexp2(acc[Mt][0][r1]) };   // e^-zi
        float2v Ef = { fexp2(acc[Mt][1][r0]), fexp2(acc[Mt][1][r1]) };   // e^-zf
        float2v Eg = { fexp2(-acc[Mt][2][r0]), fexp2(-acc[Mt][2][r1]) }; // e^-2zg
        float2v Eo = { fexp2(acc[Mt][3][r0]), fexp2(acc[Mt][3][r1]) };   // e^-zo
        float2v cprev = { c[ci], c[ci + 1] };
        float2v Di = Ei + 1.f;
        float2v Df = Ef + 1.f;
        float2v Dg = Eg + 1.f;
        float2v Dig = Di * Dg;
        float2v num = Df * (1.f - Eg) + cprev * Dig;
        float2v den = Df * Dig;
        float2v rr1 = { frcp(den.x), frcp(den.y) };
        float2v cc  = num * rr1;                  // sigma(f)c + sigma(i)tanh(g)
        c[ci] = cc.x; c[ci + 1] = cc.y;
        // clamp: equivalent to min(cc*-2l2e, 126) since -2l2e < 0
        float2v ccl = { fmaxf(cc.x, -43.668f), fmaxf(cc.y, -43.668f) };
        float2v carg = ccl * (-2.f * LOG2E);
        float2v Ec = { fexp2(carg.x), fexp2(carg.y) };                   // e^-2c
        float2v d2 = (Eo + 1.f) * (Ec + 1.f);
        float2v rr2 = { frcp(d2.x), frcp(d2.y) };
        float2v hh = (1.f - Ec) * rr2;
        h_lds[1 - pb][(Mt * 16 + quad * 4 + r0) * 136 + kw + l16] = (_Float16)hh.x;
        h_lds[1 - pb][(Mt * 16 + quad * 4 + r1) * 136 + kw + l16] = (_Float16)hh.y;
      }
    }
    __syncthreads();
  }

  // final h_192 is in buffer 0 (192 even). Store fp16 q/k.
  _Float16* dst = (isq ? q_buf : k_buf) + (size_t)head * NSEQ * DM;
  for (int idx = tid; idx < 32 * DM; idx += 512) {
    const int nl = idx >> 7, kk = idx & 127;
    dst[(size_t)(n0 + nl) * DM + kk] = h_lds[0][nl * 136 + kk];
  }
}

// ---------------------------------------------------------------------------
// Kernel 3: attention for one (head, batch, 32-row s-tile).
// ---------------------------------------------------------------------------
__global__ void attn_kernel(const float* __restrict__ graph,
                            const _Float16* __restrict__ q_buf,
                            const _Float16* __restrict__ k_buf,
                            const float* __restrict__ v_buf,
                            float* __restrict__ out) {
  __shared__ float scores_lds[32 * 337];   // [srow][t], t padded to 337
  __shared__ float v_lds[16 * 196];        // [t_local][l], stride 196

  const int bid = blockIdx.x;
  const int h  = bid / (BATCH * 11);
  const int rem = bid % (BATCH * 11);
  const int b  = rem / 11;
  const int st = rem % 11;
  const int s0 = st * 32;

  const int tid  = threadIdx.x;
  const int w    = tid >> 6;      // wave 0..3
  const int lane = tid & 63;
  const int l16  = lane & 15;
  const int quad = lane >> 4;

  // --- A fragments: q rows (fp16) ---
  half8 aq[2][4];
#pragma unroll
  for (int Mt = 0; Mt < 2; ++Mt) {
    int sg = s0 + Mt * 16 + l16; if (sg > SLEN - 1) sg = SLEN - 1;
    const _Float16* qrow = q_buf + ((size_t)h * NSEQ + (size_t)b * SLEN + sg) * DM;
#pragma unroll
    for (int kc = 0; kc < 4; ++kc)
      aq[Mt][kc] = *(const half8*)&qrow[kc * 32 + quad * 8];
  }

  // --- Phase A: 21 t-tiles of 16, round-robin over 4 waves ---
  for (int tt = w; tt < 21; tt += 4) {
    const int T0t = tt * 16;
    int tgc = T0t + l16; if (tgc > SLEN - 1) tgc = SLEN - 1;
    const _Float16* krow = k_buf + ((size_t)h * NSEQ + (size_t)b * SLEN + tgc) * DM;
    half8 bf[4];
#pragma unroll
    for (int kc = 0; kc < 4; ++kc)
      bf[kc] = *(const half8*)&krow[kc * 32 + quad * 8];
    floatx4 sacc0 = {0.f, 0.f, 0.f, 0.f};
    floatx4 sacc1 = {0.f, 0.f, 0.f, 0.f};
#pragma unroll
    for (int kc = 0; kc < 4; ++kc) {
      sacc0 = __builtin_amdgcn_mfma_f32_16x16x32_f16(aq[0][kc], bf[kc], sacc0, 0, 0, 0);
      sacc1 = __builtin_amdgcn_mfma_f32_16x16x32_f16(aq[1][kc], bf[kc], sacc1, 0, 0, 0);
    }
#pragma unroll
    for (int Mt = 0; Mt < 2; ++Mt) {
#pragma unroll
      for (int r = 0; r < 4; ++r) {
        const int srow = Mt * 16 + quad * 4 + r;
        const int tcol = T0t + l16;
        float sc = (Mt == 0 ? sacc0[r] : sacc1[r]) * 0.088388347648318447f;
        float lk = (sc >= 0.f) ? sc : 0.2f * sc;
        const int sg = s0 + srow;
        if (tcol < SLEN && sg < SLEN) {
          float gv = graph[(size_t)tcol * SLEN + sg];      // graph.T
          if (!(gv != 0.f || tcol == sg)) lk += -1000000000.0f;
        }
        scores_lds[srow * 337 + tcol] = lk;
      }
    }
  }
  __syncthreads();

  // --- softmax: 8 threads per row ---
  {
    const int r = tid >> 3, sub = tid & 7;
    float m = -3.0e38f;
    for (int t = sub; t < SLEN; t += 8) m = fmaxf(m, scores_lds[r * 337 + t]);
#pragma unroll
    for (int o = 1; o < 8; o <<= 1) m = fmaxf(m, __shfl_xor(m, o));
    float ssum = 0.f;
    for (int t = sub; t < SLEN; t += 8) {
      float e = fexp2((scores_lds[r * 337 + t] - m) * LOG2E);
      scores_lds[r * 337 + t] = e;
      ssum += e;
    }
#pragma unroll
    for (int o = 1; o < 8; o <<= 1) ssum += __shfl_xor(ssum, o);
    float inv = frcp(ssum);
    for (int t = sub; t < SLEN; t += 8) scores_lds[r * 337 + t] *= inv;
  }
  __syncthreads();

  // --- Phase B: out[s][l] = sum_t p[s][t] * v[t][l] ---
  const int s_l = tid & 31;
  const int lg  = tid >> 5;                 // 0..7 -> l block of 24
  float oacc[24];
#pragma unroll
  for (int j = 0; j < 24; ++j) oacc[j] = 0.f;

  for (int T0 = 0; T0 < SLEN; T0 += 16) {
    __syncthreads();
    for (int idx = tid; idx < 16 * LSTEPS; idx += 256) {
      int tl = idx & 15, lx = idx >> 4;
      int t = T0 + tl;
      v_lds[tl * 196 + lx] = (t < SLEN)
        ? v_buf[(size_t)h * LSTEPS * NSEQ + (size_t)lx * NSEQ + (size_t)b * SLEN + t]
        : 0.f;
    }
    __syncthreads();
    const int tmax = (SLEN - T0 < 16) ? (SLEN - T0) : 16;
    for (int tl = 0; tl < tmax; ++tl) {
      float p = scores_lds[s_l * 337 + T0 + tl];
      const float* vr = &v_lds[tl * 196 + lg * 24];
#pragma unroll
      for (int j4 = 0; j4 < 6; ++j4) {
        float4 vv = *(const float4*)&vr[j4 * 4];
        oacc[j4 * 4 + 0] = fmaf(p, vv.x, oacc[j4 * 4 + 0]);
        oacc[j4 * 4 + 1] = fmaf(p, vv.y, oacc[j4 * 4 + 1]);
        oacc[j4 * 4 + 2] = fmaf(p, vv.z, oacc[j4 * 4 + 2]);
        oacc[j4 * 4 + 3] = fmaf(p, vv.w, oacc[j4 * 4 + 3]);
      }
    }
  }

  // --- epilogue: leaky + store [B][S][L][H] as fp32 ---
  const int sg = s0 + s_l;
  if (sg < SLEN) {
    size_t base = (((size_t)b * SLEN + sg) * LSTEPS + lg * 24) * HEADS + h;
#pragma unroll
    for (int j = 0; j < 24; ++j) {
      float v = oacc[j];
      v = (v >= 0.f) ? v : 0.2f * v;
      out[base + (size_t)j * HEADS] = v;
    }
  }
}

// ---------------------------------------------------------------------------
extern "C" void kernel_launch(void* const* d_in, const int* in_sizes, int n_in,
                              void* d_out, int out_size, void* d_ws, size_t ws_size,
                              hipStream_t stream) {
  const float* x     = (const float*)d_in[0];
  const float* graph = (const float*)d_in[1];
  const float* qWih  = (const float*)d_in[2];
  const float* qWhh  = (const float*)d_in[3];
  const float* qbih  = (const float*)d_in[4];
  const float* qbhh  = (const float*)d_in[5];
  const float* kWih  = (const float*)d_in[6];
  const float* kWhh  = (const float*)d_in[7];
  const float* kbih  = (const float*)d_in[8];
  const float* kbhh  = (const float*)d_in[9];
  const float* vWih  = (const float*)d_in[10];
  const float* vWhh  = (const float*)d_in[11];
  const float* vbih  = (const float*)d_in[12];
  const float* vbhh  = (const float*)d_in[13];

  // workspace layout
  const size_t v_bytes = (size_t)HEADS * LSTEPS * NSEQ * sizeof(float);   // 63,897,600
  const size_t qk_bytes = (size_t)HEADS * NSEQ * DM * sizeof(_Float16);   // 21,299,200
  float*    v_buf = (float*)d_ws;
  _Float16* q_buf = (_Float16*)((char*)d_ws + v_bytes);
  _Float16* k_buf = (_Float16*)((char*)d_ws + v_bytes + qk_bytes);
  float* out = (float*)d_out;

  v_lstm_kernel<<<dim3((HEADS * NSEQ + 255) / 256), dim3(256), 0, stream>>>(
      x, vWih, vWhh, vbih, vbhh, v_buf);

  qk_lstm_kernel<<<dim3(16 * 325), dim3(512), 0, stream>>>(
      qWih, qWhh, qbih, qbhh, kWih, kWhh, kbih, kbhh, x, q_buf, k_buf);

  attn_kernel<<<dim3(HEADS * BATCH * 11), dim3(256), 0, stream>>>(
      graph, q_buf, k_buf, v_buf, out);
}

// Round 4
// 7501.150 us; speedup vs baseline: 1.0635x; 1.0635x over previous
//
#include <hip/hip_runtime.h>
#include <hip/hip_bf16.h>

// Problem constants
#define HEADS  8
#define BATCH  32
#define SLEN   325
#define LSTEPS 192
#define DM     128
#define NSEQ   (BATCH*SLEN)          // 10400
#define LOG2E  1.4426950408889634f

typedef _Float16 half8  __attribute__((ext_vector_type(8)));
typedef _Float16 half4t __attribute__((ext_vector_type(4)));
typedef float    floatx4 __attribute__((ext_vector_type(4)));

__device__ __forceinline__ float fexp2(float x) { return __builtin_amdgcn_exp2f(x); }
__device__ __forceinline__ float frcp(float x)  { return __builtin_amdgcn_rcpf(x); }
// z' = -log2e * z  ->  sigmoid(z)
__device__ __forceinline__ float sigm_pre(float zs) { return frcp(1.f + fexp2(zs)); }
// z' = 2*log2e * z ->  tanh(z)
__device__ __forceinline__ float tanh_pre(float zs) { return 1.f - 2.f*frcp(1.f + fexp2(zs)); }

// ---------------------------------------------------------------------------
// Kernel 1: v-LSTM (hidden size 1), one thread per (head, sequence).
// ---------------------------------------------------------------------------
__global__ void v_lstm_kernel(const float* __restrict__ x,
                              const float* __restrict__ vWih,
                              const float* __restrict__ vWhh,
                              const float* __restrict__ vbih,
                              const float* __restrict__ vbhh,
                              float* __restrict__ v_buf) {
  int gid = blockIdx.x * 256 + threadIdx.x;
  if (gid >= HEADS * NSEQ) return;
  int hh = gid / NSEQ;
  int n  = gid - hh * NSEQ;

  float wih[4], whh[4], bb[4];
#pragma unroll
  for (int g = 0; g < 4; ++g) {
    float sc = (g == 2) ? 2.f*LOG2E : -LOG2E;
    wih[g] = vWih[hh*4+g] * sc;
    whh[g] = vWhh[hh*4+g] * sc;
    bb[g]  = (vbih[hh*4+g] + vbhh[hh*4+g]) * sc;
  }
  const float* xr = x + (size_t)n * LSTEPS;
  float* vo = v_buf + (size_t)hh * LSTEPS * NSEQ + n;
  float hpr = 0.f, c = 0.f;
  for (int t = 0; t < LSTEPS; ++t) {
    float xt = xr[t];
    float zi = fmaf(wih[0], xt, fmaf(whh[0], hpr, bb[0]));
    float zf = fmaf(wih[1], xt, fmaf(whh[1], hpr, bb[1]));
    float zg = fmaf(wih[2], xt, fmaf(whh[2], hpr, bb[2]));
    float zo = fmaf(wih[3], xt, fmaf(whh[3], hpr, bb[3]));
    float si = sigm_pre(zi), sf = sigm_pre(zf), so = sigm_pre(zo);
    float tg = tanh_pre(zg);
    c = fmaf(sf, c, si * tg);
    float tc = tanh_pre(2.f*LOG2E*c);
    hpr = so * tc;
    vo[(size_t)t * NSEQ] = hpr;
  }
}

// ---------------------------------------------------------------------------
// Kernel 2: q/k LSTMs via fp16 MFMA.
//
// R10 (scale rows-per-step): session data shows per-CU throughput pinned at
// ~64 rows per ~9300-cyc step across R6 (64 rows, 1 blk), R8 (2x32 rows),
// R9 (2x32, packed math) -- with NO unit saturated (VALU 47-58%, LDS ~40%,
// MFMA ~25%). Latency-bound per step; co-resident blocks do NOT fill the
// stalls (R8), fewer VALU ops don't shrink the wall (R9: VALU 60->47 but
// dur WORSE; packed-math reverted). So: put MORE rows in one block at the
// same occupancy -> Mt=6, 96 rows/block, one block/CU.
//
// Register honesty (R7 lesson: cap below demand -> bfrag to scratch -> GBs
// of HBM): bfrag 48 (gate-0 streamed from LDS) + acc 96 + c 24 + scalars/
// addr ~30 = ~200 <= 256 cap from __launch_bounds__(512,2). Margin ~50.
// LDS: x 36K + h dbuf 51K + w0 32K = 119 KB (1 block/CU; 128KiB-static
// precedent on gfx950). Grid 16*109=1744, tail tile (32 valid rows) guarded
// on x-stage and store; LSTM on zero-x pad rows stays finite.
//
// Watch: FETCH > ~1 GB => spilled after all -> retreat to Mt=5.
//        dur ~7.5ms unchanged + VALU ~70% => wall scales per-row -> pivot.
// ---------------------------------------------------------------------------
#define MT    6
#define ROWS  (MT*16)                  // 96 rows per block
#define NTILE 109                      // ceil(10400/96)

__global__ __launch_bounds__(512, 2)
void qk_lstm_kernel(const float* __restrict__ qWih, const float* __restrict__ qWhh,
                    const float* __restrict__ qbih, const float* __restrict__ qbhh,
                    const float* __restrict__ kWih, const float* __restrict__ kWhh,
                    const float* __restrict__ kbih, const float* __restrict__ kbhh,
                    const float* __restrict__ x,
                    _Float16* __restrict__ q_buf, _Float16* __restrict__ k_buf) {
  __shared__ _Float16 x_lds[LSTEPS * ROWS];      // [t][row], fp16, 36 KB
  __shared__ _Float16 h_lds[2][ROWS * 136];      // [buf][row][kk], pad 136, 51 KB
  __shared__ half8    w0_lds[8 * 4 * 64];        // [wave][kc][lane] gate-0 B frags, 32 KB

  const int lsi = blockIdx.x / NTILE;            // 0..15 : q heads 0-7 then k heads 0-7
  const int n0  = (blockIdx.x % NTILE) * ROWS;
  const int head = lsi & 7;
  const bool isq = lsi < 8;
  const float* Wih = (isq ? qWih : kWih) + head * 512;
  const float* Whh = (isq ? qWhh : kWhh) + (size_t)head * 512 * 128;
  const float* bih = (isq ? qbih : kbih) + head * 512;
  const float* bhh = (isq ? qbhh : kbhh) + head * 512;

  const int tid  = threadIdx.x;
  const int w    = tid >> 6;       // wave 0..7
  const int lane = tid & 63;
  const int l16  = lane & 15;
  const int quad = lane >> 4;      // 0..3
  const int kw   = w * 16;         // wave's kk slice base

  // --- load W^T fragments (pre-scaled); gate 0 -> LDS, gates 1..3 -> regs ---
  half8 bfrag[3][4];               // [gate-1][kchunk] = 48 VGPRs
  float wih_s[4], b_s[4];
#pragma unroll
  for (int g = 0; g < 4; ++g) {
    const float sc = (g == 2) ? 2.f*LOG2E : -LOG2E;
    const int col = g * 128 + kw + l16;          // global z column
    wih_s[g] = Wih[col] * sc;
    b_s[g]   = (bih[col] + bhh[col]) * sc;
#pragma unroll
    for (int kc = 0; kc < 4; ++kc) {
      const int k0 = kc * 32 + quad * 8;
      const float4 v0 = *(const float4*)&Whh[(size_t)col * 128 + k0];
      const float4 v1 = *(const float4*)&Whh[(size_t)col * 128 + k0 + 4];
      half8 f;
      f[0] = (_Float16)(v0.x * sc); f[1] = (_Float16)(v0.y * sc);
      f[2] = (_Float16)(v0.z * sc); f[3] = (_Float16)(v0.w * sc);
      f[4] = (_Float16)(v1.x * sc); f[5] = (_Float16)(v1.y * sc);
      f[6] = (_Float16)(v1.z * sc); f[7] = (_Float16)(v1.w * sc);
      if (g == 0) w0_lds[(w * 4 + kc) * 64 + lane] = f;   // lane-linear, 16B/lane
      else        bfrag[g - 1][kc] = f;
    }
  }

  // --- stage x transposed into LDS (full 192 steps), coalesced float4 ---
  for (int u = tid; u < ROWS * 48; u += 512) {
    const int rr = u / 48, tq = u - rr * 48;     // tq: group of 4 steps
    const int n = n0 + rr;
    float4 xv = {0.f, 0.f, 0.f, 0.f};
    if (n < NSEQ) xv = *(const float4*)&x[(size_t)n * LSTEPS + tq * 4];
    x_lds[(tq * 4 + 0) * ROWS + rr] = (_Float16)xv.x;
    x_lds[(tq * 4 + 1) * ROWS + rr] = (_Float16)xv.y;
    x_lds[(tq * 4 + 2) * ROWS + rr] = (_Float16)xv.z;
    x_lds[(tq * 4 + 3) * ROWS + rr] = (_Float16)xv.w;
  }
  for (int idx = tid; idx < ROWS * 136; idx += 512) h_lds[0][idx] = (_Float16)0.f;
  __syncthreads();

  floatx4 acc[MT][4];              // [Mtile][gate] -> 96 accum regs
  float c[MT * 4];
#pragma unroll
  for (int i = 0; i < MT * 4; ++i) c[i] = 0.f;

  for (int t = 0; t < LSTEPS; ++t) {
    const int pb = t & 1;
    // acc init: z0 = b' + wih'*x_t   (already gate-scaled)
#pragma unroll
    for (int Mt = 0; Mt < MT; ++Mt) {
      const half4t xq = *(const half4t*)&x_lds[t * ROWS + Mt * 16 + quad * 4];
      float xv[4];
      xv[0] = (float)xq[0]; xv[1] = (float)xq[1];
      xv[2] = (float)xq[2]; xv[3] = (float)xq[3];
#pragma unroll
      for (int g = 0; g < 4; ++g)
#pragma unroll
        for (int r = 0; r < 4; ++r)
          acc[Mt][g][r] = fmaf(wih_s[g], xv[r], b_s[g]);
    }
    // MFMA: z += h @ W^T ; gate 0's B frag streamed from LDS per kc
#pragma unroll
    for (int kc = 0; kc < 4; ++kc) {
      const half8 b0 = w0_lds[(w * 4 + kc) * 64 + lane];
#pragma unroll
      for (int Mt = 0; Mt < MT; ++Mt) {
        const half8 af = *(const half8*)&h_lds[pb][(Mt * 16 + l16) * 136 + kc * 32 + quad * 8];
        acc[Mt][0] = __builtin_amdgcn_mfma_f32_16x16x32_f16(af, b0, acc[Mt][0], 0, 0, 0);
#pragma unroll
        for (int g = 1; g < 4; ++g)
          acc[Mt][g] = __builtin_amdgcn_mfma_f32_16x16x32_f16(af, bfrag[g - 1][kc], acc[Mt][g], 0, 0, 0);
      }
    }
    // 7-trans gate math (verified R5): acc0=-zi*l2e, acc1=-zf*l2e,
    // acc2=+2zg*l2e, acc3=-zo*l2e.  (R8 scalar form; R9 packed reverted.)
#pragma unroll
    for (int Mt = 0; Mt < MT; ++Mt) {
#pragma unroll
      for (int r = 0; r < 4; ++r) {
        const int ci = Mt * 4 + r;
        const float Ei = fexp2(acc[Mt][0][r]);          // e^-zi
        const float Ef = fexp2(acc[Mt][1][r]);          // e^-zf
        const float Eg = fexp2(-acc[Mt][2][r]);         // e^-2zg
        const float Eo = fexp2(acc[Mt][3][r]);          // e^-zo
        const float Di = 1.f + Ei, Df = 1.f + Ef, Dg = 1.f + Eg;
        const float Dig = Di * Dg;
        const float num = fmaf(Df, 1.f - Eg, c[ci] * Dig);
        const float cc  = num * frcp(Df * Dig);         // sigma(f)c + sigma(i)tanh(g)
        c[ci] = cc;
        const float carg = fminf(cc * (-2.f * LOG2E), 126.f);
        const float Ec = fexp2(carg);                   // e^-2c
        const float hh = (1.f - Ec) * frcp((1.f + Eo) * (1.f + Ec));
        h_lds[1 - pb][(Mt * 16 + quad * 4 + r) * 136 + kw + l16] = (_Float16)hh;
      }
    }
    __syncthreads();
  }

  // final h_192 is in buffer 0 (192 even). Store fp16 q/k.
  _Float16* dst = (isq ? q_buf : k_buf) + (size_t)head * NSEQ * DM;
  for (int idx = tid; idx < ROWS * DM; idx += 512) {
    const int nl = idx >> 7, kk = idx & 127;
    const int n = n0 + nl;
    if (n < NSEQ) dst[(size_t)n * DM + kk] = h_lds[0][nl * 136 + kk];
  }
}

// ---------------------------------------------------------------------------
// Kernel 3: attention for one (head, batch, 32-row s-tile).
// ---------------------------------------------------------------------------
__global__ void attn_kernel(const float* __restrict__ graph,
                            const _Float16* __restrict__ q_buf,
                            const _Float16* __restrict__ k_buf,
                            const float* __restrict__ v_buf,
                            float* __restrict__ out) {
  __shared__ float scores_lds[32 * 337];   // [srow][t], t padded to 337
  __shared__ float v_lds[16 * 196];        // [t_local][l], stride 196

  const int bid = blockIdx.x;
  const int h  = bid / (BATCH * 11);
  const int rem = bid % (BATCH * 11);
  const int b  = rem / 11;
  const int st = rem % 11;
  const int s0 = st * 32;

  const int tid  = threadIdx.x;
  const int w    = tid >> 6;      // wave 0..3
  const int lane = tid & 63;
  const int l16  = lane & 15;
  const int quad = lane >> 4;

  // --- A fragments: q rows (fp16) ---
  half8 aq[2][4];
#pragma unroll
  for (int Mt = 0; Mt < 2; ++Mt) {
    int sg = s0 + Mt * 16 + l16; if (sg > SLEN - 1) sg = SLEN - 1;
    const _Float16* qrow = q_buf + ((size_t)h * NSEQ + (size_t)b * SLEN + sg) * DM;
#pragma unroll
    for (int kc = 0; kc < 4; ++kc)
      aq[Mt][kc] = *(const half8*)&qrow[kc * 32 + quad * 8];
  }

  // --- Phase A: 21 t-tiles of 16, round-robin over 4 waves ---
  for (int tt = w; tt < 21; tt += 4) {
    const int T0t = tt * 16;
    int tgc = T0t + l16; if (tgc > SLEN - 1) tgc = SLEN - 1;
    const _Float16* krow = k_buf + ((size_t)h * NSEQ + (size_t)b * SLEN + tgc) * DM;
    half8 bf[4];
#pragma unroll
    for (int kc = 0; kc < 4; ++kc)
      bf[kc] = *(const half8*)&krow[kc * 32 + quad * 8];
    floatx4 sacc0 = {0.f, 0.f, 0.f, 0.f};
    floatx4 sacc1 = {0.f, 0.f, 0.f, 0.f};
#pragma unroll
    for (int kc = 0; kc < 4; ++kc) {
      sacc0 = __builtin_amdgcn_mfma_f32_16x16x32_f16(aq[0][kc], bf[kc], sacc0, 0, 0, 0);
      sacc1 = __builtin_amdgcn_mfma_f32_16x16x32_f16(aq[1][kc], bf[kc], sacc1, 0, 0, 0);
    }
#pragma unroll
    for (int Mt = 0; Mt < 2; ++Mt) {
#pragma unroll
      for (int r = 0; r < 4; ++r) {
        const int srow = Mt * 16 + quad * 4 + r;
        const int tcol = T0t + l16;
        float sc = (Mt == 0 ? sacc0[r] : sacc1[r]) * 0.088388347648318447f;
        float lk = (sc >= 0.f) ? sc : 0.2f * sc;
        const int sg = s0 + srow;
        if (tcol < SLEN && sg < SLEN) {
          float gv = graph[(size_t)tcol * SLEN + sg];      // graph.T
          if (!(gv != 0.f || tcol == sg)) lk += -1000000000.0f;
        }
        scores_lds[srow * 337 + tcol] = lk;
      }
    }
  }
  __syncthreads();

  // --- softmax: 8 threads per row ---
  {
    const int r = tid >> 3, sub = tid & 7;
    float m = -3.0e38f;
    for (int t = sub; t < SLEN; t += 8) m = fmaxf(m, scores_lds[r * 337 + t]);
#pragma unroll
    for (int o = 1; o < 8; o <<= 1) m = fmaxf(m, __shfl_xor(m, o));
    float ssum = 0.f;
    for (int t = sub; t < SLEN; t += 8) {
      float e = fexp2((scores_lds[r * 337 + t] - m) * LOG2E);
      scores_lds[r * 337 + t] = e;
      ssum += e;
    }
#pragma unroll
    for (int o = 1; o < 8; o <<= 1) ssum += __shfl_xor(ssum, o);
    float inv = frcp(ssum);
    for (int t = sub; t < SLEN; t += 8) scores_lds[r * 337 + t] *= inv;
  }
  __syncthreads();

  // --- Phase B: out[s][l] = sum_t p[s][t] * v[t][l] ---
  const int s_l = tid & 31;
  const int lg  = tid >> 5;                 // 0..7 -> l block of 24
  float oacc[24];
#pragma unroll
  for (int j = 0; j < 24; ++j) oacc[j] = 0.f;

  for (int T0 = 0; T0 < SLEN; T0 += 16) {
    __syncthreads();
    for (int idx = tid; idx < 16 * LSTEPS; idx += 256) {
      int tl = idx & 15, lx = idx >> 4;
      int t = T0 + tl;
      v_lds[tl * 196 + lx] = (t < SLEN)
        ? v_buf[(size_t)h * LSTEPS * NSEQ + (size_t)lx * NSEQ + (size_t)b * SLEN + t]
        : 0.f;
    }
    __syncthreads();
    const int tmax = (SLEN - T0 < 16) ? (SLEN - T0) : 16;
    for (int tl = 0; tl < tmax; ++tl) {
      float p = scores_lds[s_l * 337 + T0 + tl];
      const float* vr = &v_lds[tl * 196 + lg * 24];
#pragma unroll
      for (int j4 = 0; j4 < 6; ++j4) {
        float4 vv = *(const float4*)&vr[j4 * 4];
        oacc[j4 * 4 + 0] = fmaf(p, vv.x, oacc[j4 * 4 + 0]);
        oacc[j4 * 4 + 1] = fmaf(p, vv.y, oacc[j4 * 4 + 1]);
        oacc[j4 * 4 + 2] = fmaf(p, vv.z, oacc[j4 * 4 + 2]);
        oacc[j4 * 4 + 3] = fmaf(p, vv.w, oacc[j4 * 4 + 3]);
      }
    }
  }

  // --- epilogue: leaky + store [B][S][L][H] as fp32 ---
  const int sg = s0 + s_l;
  if (sg < SLEN) {
    size_t base = (((size_t)b * SLEN + sg) * LSTEPS + lg * 24) * HEADS + h;
#pragma unroll
    for (int j = 0; j < 24; ++j) {
      float v = oacc[j];
      v = (v >= 0.f) ? v : 0.2f * v;
      out[base + (size_t)j * HEADS] = v;
    }
  }
}

// ---------------------------------------------------------------------------
extern "C" void kernel_launch(void* const* d_in, const int* in_sizes, int n_in,
                              void* d_out, int out_size, void* d_ws, size_t ws_size,
                              hipStream_t stream) {
  const float* x     = (const float*)d_in[0];
  const float* graph = (const float*)d_in[1];
  const float* qWih  = (const float*)d_in[2];
  const float* qWhh  = (const float*)d_in[3];
  const float* qbih  = (const float*)d_in[4];
  const float* qbhh  = (const float*)d_in[5];
  const float* kWih  = (const float*)d_in[6];
  const float* kWhh  = (const float*)d_in[7];
  const float* kbih  = (const float*)d_in[8];
  const float* kbhh  = (const float*)d_in[9];
  const float* vWih  = (const float*)d_in[10];
  const float* vWhh  = (const float*)d_in[11];
  const float* vbih  = (const float*)d_in[12];
  const float* vbhh  = (const float*)d_in[13];

  // workspace layout
  const size_t v_bytes = (size_t)HEADS * LSTEPS * NSEQ * sizeof(float);   // 63,897,600
  const size_t qk_bytes = (size_t)HEADS * NSEQ * DM * sizeof(_Float16);   // 21,299,200
  float*    v_buf = (float*)d_ws;
  _Float16* q_buf = (_Float16*)((char*)d_ws + v_bytes);
  _Float16* k_buf = (_Float16*)((char*)d_ws + v_bytes + qk_bytes);
  float* out = (float*)d_out;

  v_lstm_kernel<<<dim3((HEADS * NSEQ + 255) / 256), dim3(256), 0, stream>>>(
      x, vWih, vWhh, vbih, vbhh, v_buf);

  qk_lstm_kernel<<<dim3(16 * NTILE), dim3(512), 0, stream>>>(
      qWih, qWhh, qbih, qbhh, kWih, kWhh, kbih, kbhh, x, q_buf, k_buf);

  attn_kernel<<<dim3(HEADS * BATCH * 11), dim3(256), 0, stream>>>(
      graph, q_buf, k_buf, v_buf, out);
}

// Round 5
// 6645.325 us; speedup vs baseline: 1.2005x; 1.1288x over previous
//
#include <hip/hip_runtime.h>
#include <hip/hip_bf16.h>

// Problem constants
#define HEADS  8
#define BATCH  32
#define SLEN   325
#define LSTEPS 192
#define DM     128
#define NSEQ   (BATCH*SLEN)          // 10400
#define LOG2E  1.4426950408889634f

typedef _Float16 half8  __attribute__((ext_vector_type(8)));
typedef _Float16 half4t __attribute__((ext_vector_type(4)));
typedef float    floatx4 __attribute__((ext_vector_type(4)));
typedef float    float2v __attribute__((ext_vector_type(2)));

__device__ __forceinline__ float fexp2(float x) { return __builtin_amdgcn_exp2f(x); }
__device__ __forceinline__ float frcp(float x)  { return __builtin_amdgcn_rcpf(x); }
// z' = -log2e * z  ->  sigmoid(z)
__device__ __forceinline__ float sigm_pre(float zs) { return frcp(1.f + fexp2(zs)); }
// z' = 2*log2e * z ->  tanh(z)
__device__ __forceinline__ float tanh_pre(float zs) { return 1.f - 2.f*frcp(1.f + fexp2(zs)); }

// ---------------------------------------------------------------------------
// Kernel 1: v-LSTM (hidden size 1), one thread per (head, sequence).
// ---------------------------------------------------------------------------
__global__ void v_lstm_kernel(const float* __restrict__ x,
                              const float* __restrict__ vWih,
                              const float* __restrict__ vWhh,
                              const float* __restrict__ vbih,
                              const float* __restrict__ vbhh,
                              float* __restrict__ v_buf) {
  int gid = blockIdx.x * 256 + threadIdx.x;
  if (gid >= HEADS * NSEQ) return;
  int hh = gid / NSEQ;
  int n  = gid - hh * NSEQ;

  float wih[4], whh[4], bb[4];
#pragma unroll
  for (int g = 0; g < 4; ++g) {
    float sc = (g == 2) ? 2.f*LOG2E : -LOG2E;
    wih[g] = vWih[hh*4+g] * sc;
    whh[g] = vWhh[hh*4+g] * sc;
    bb[g]  = (vbih[hh*4+g] + vbhh[hh*4+g]) * sc;
  }
  const float* xr = x + (size_t)n * LSTEPS;
  float* vo = v_buf + (size_t)hh * LSTEPS * NSEQ + n;
  float hpr = 0.f, c = 0.f;
  for (int t = 0; t < LSTEPS; ++t) {
    float xt = xr[t];
    float zi = fmaf(wih[0], xt, fmaf(whh[0], hpr, bb[0]));
    float zf = fmaf(wih[1], xt, fmaf(whh[1], hpr, bb[1]));
    float zg = fmaf(wih[2], xt, fmaf(whh[2], hpr, bb[2]));
    float zo = fmaf(wih[3], xt, fmaf(whh[3], hpr, bb[3]));
    float si = sigm_pre(zi), sf = sigm_pre(zf), so = sigm_pre(zo);
    float tg = tanh_pre(zg);
    c = fmaf(sf, c, si * tg);
    float tc = tanh_pre(2.f*LOG2E*c);
    hpr = so * tc;
    vo[(size_t)t * NSEQ] = hpr;
  }
}

// ---------------------------------------------------------------------------
// Kernel 2: q/k LSTMs via fp16 MFMA.
//
// R11 (clean packed-math test): session law so far -- per-row wall cost is
// CONSTANT ~145 CU-cyc/row-step across R6 (64r x 1blk), R8 (32r x 2blk),
// R10 (96r x 1blk): throughput-bound on issued work, not latency, not
// occupancy. R9 proved packing CUTS issue (VALU 60.6->46.9) but was voided
// by spill (128-reg cap + float2 temps -> FETCH 92->190MB). This round:
// R0's proven Mt=4 structure (176 regs, 2 waves/SIMD, cap 256 -> ~80 reg
// headroom) + packed-f32 gate math as the ONLY change. float2v over acc
// r-pairs -> v_pk_{add,mul,fma}_f32 on aligned VGPR pairs (acc floatx4 is
// contiguous, (r0,r1)/(r2,r3) are 64b-aligned pairs).
//
// Falsification: FETCH > 1GB -> spilled, experiment void, revert.
//                no spill + VALU down + dur flat -> NOT issue-bound ->
//                structural trans/dependency floor -> roofline.
//
// NOTE (R3/R5/R6/R7): never cap regs below structural demand (bfrag ->
// scratch -> GBs of HBM). Mt=4 demand ~176+temps; (512,2) cap 256. OK.
// ---------------------------------------------------------------------------
__global__ __launch_bounds__(512, 2)
void qk_lstm_kernel(const float* __restrict__ qWih, const float* __restrict__ qWhh,
                    const float* __restrict__ qbih, const float* __restrict__ qbhh,
                    const float* __restrict__ kWih, const float* __restrict__ kWhh,
                    const float* __restrict__ kbih, const float* __restrict__ kbhh,
                    const float* __restrict__ x,
                    _Float16* __restrict__ q_buf, _Float16* __restrict__ k_buf) {
  __shared__ _Float16 x_lds[LSTEPS * 64];        // [t][n_local], fp16, 24.0 KB
  __shared__ _Float16 h_lds[2][64 * 136];        // [buf][row][kk], pad 136, 34.0 KB

  const int lsi = blockIdx.x / 163;              // 0..15 : q heads 0-7 then k heads 0-7
  const int n0  = (blockIdx.x % 163) * 64;
  const int head = lsi & 7;
  const bool isq = lsi < 8;
  const float* Wih = (isq ? qWih : kWih) + head * 512;
  const float* Whh = (isq ? qWhh : kWhh) + (size_t)head * 512 * 128;
  const float* bih = (isq ? qbih : kbih) + head * 512;
  const float* bhh = (isq ? qbhh : kbhh) + head * 512;

  const int tid  = threadIdx.x;
  const int w    = tid >> 6;       // wave 0..7
  const int lane = tid & 63;
  const int l16  = lane & 15;
  const int quad = lane >> 4;      // 0..3
  const int kw   = w * 16;         // wave's kk slice base

  // --- load W^T fragments (pre-scaled) + per-lane bias/wih scalars ---
  half8 bfrag[4][4];               // [gate][kchunk] = 64 VGPRs, register-resident
  float wih_s[4], b_s[4];
#pragma unroll
  for (int g = 0; g < 4; ++g) {
    const float sc = (g == 2) ? 2.f*LOG2E : -LOG2E;
    const int col = g * 128 + kw + l16;          // global z column
    wih_s[g] = Wih[col] * sc;
    b_s[g]   = (bih[col] + bhh[col]) * sc;
#pragma unroll
    for (int kc = 0; kc < 4; ++kc) {
      const int k0 = kc * 32 + quad * 8;
      const float4 v0 = *(const float4*)&Whh[(size_t)col * 128 + k0];
      const float4 v1 = *(const float4*)&Whh[(size_t)col * 128 + k0 + 4];
      half8 f;
      f[0] = (_Float16)(v0.x * sc); f[1] = (_Float16)(v0.y * sc);
      f[2] = (_Float16)(v0.z * sc); f[3] = (_Float16)(v0.w * sc);
      f[4] = (_Float16)(v1.x * sc); f[5] = (_Float16)(v1.y * sc);
      f[6] = (_Float16)(v1.z * sc); f[7] = (_Float16)(v1.w * sc);
      bfrag[g][kc] = f;
    }
  }

  // --- stage x transposed into LDS (full 192 steps), coalesced float4 ---
  for (int u = tid; u < 64 * 48; u += 512) {
    const int rr = u / 48, tq = u - rr * 48;     // tq: group of 4 steps
    const int n = n0 + rr;
    float4 xv = {0.f, 0.f, 0.f, 0.f};
    if (n < NSEQ) xv = *(const float4*)&x[(size_t)n * LSTEPS + tq * 4];
    x_lds[(tq * 4 + 0) * 64 + rr] = (_Float16)xv.x;
    x_lds[(tq * 4 + 1) * 64 + rr] = (_Float16)xv.y;
    x_lds[(tq * 4 + 2) * 64 + rr] = (_Float16)xv.z;
    x_lds[(tq * 4 + 3) * 64 + rr] = (_Float16)xv.w;
  }
  for (int idx = tid; idx < 64 * 136; idx += 512) h_lds[0][idx] = (_Float16)0.f;
  __syncthreads();

  floatx4 acc[4][4];               // [Mtile][gate] -> 64 accum regs
  float c[16];
#pragma unroll
  for (int i = 0; i < 16; ++i) c[i] = 0.f;

  for (int t = 0; t < LSTEPS; ++t) {
    const int pb = t & 1;
    // acc init: z0 = b' + wih'*x_t (vector form -> packed fma pairs)
#pragma unroll
    for (int Mt = 0; Mt < 4; ++Mt) {
      const half4t xq = *(const half4t*)&x_lds[t * 64 + Mt * 16 + quad * 4];
      floatx4 xv4;
      xv4[0] = (float)xq[0]; xv4[1] = (float)xq[1];
      xv4[2] = (float)xq[2]; xv4[3] = (float)xq[3];
#pragma unroll
      for (int g = 0; g < 4; ++g)
        acc[Mt][g] = xv4 * wih_s[g] + b_s[g];
    }
    // MFMA: z += h @ W^T  (16 independent acc chains across Mt x gate)
#pragma unroll
    for (int kc = 0; kc < 4; ++kc) {
#pragma unroll
      for (int Mt = 0; Mt < 4; ++Mt) {
        const half8 af = *(const half8*)&h_lds[pb][(Mt * 16 + l16) * 136 + kc * 32 + quad * 8];
#pragma unroll
        for (int g = 0; g < 4; ++g)
          acc[Mt][g] = __builtin_amdgcn_mfma_f32_16x16x32_f16(af, bfrag[g][kc], acc[Mt][g], 0, 0, 0);
      }
    }
    // Packed-f32 gate math over row pairs (2p, 2p+1). Same algebra as the
    // verified R5 7-trans form: acc0=-zi*l2e, acc1=-zf*l2e, acc2=+2zg*l2e,
    // acc3=-zo*l2e. (r0,r1) and (r2,r3) are aligned VGPR pairs inside the
    // floatx4 acc -> v_pk_{add,mul,fma}_f32. Trans stays scalar (no packed
    // exp/rcp exists). Clamp via fmaxf(cc,-43.668) == min(carg,126).
#pragma unroll
    for (int Mt = 0; Mt < 4; ++Mt) {
#pragma unroll
      for (int p = 0; p < 2; ++p) {
        const int r0 = 2 * p, r1 = 2 * p + 1;
        const int ci = Mt * 4 + r0;
        float2v Ei = { fexp2(acc[Mt][0][r0]), fexp2(acc[Mt][0][r1]) };   // e^-zi
        float2v Ef = { fexp2(acc[Mt][1][r0]), fexp2(acc[Mt][1][r1]) };   // e^-zf
        float2v Eg = { fexp2(-acc[Mt][2][r0]), fexp2(-acc[Mt][2][r1]) }; // e^-2zg
        float2v Eo = { fexp2(acc[Mt][3][r0]), fexp2(acc[Mt][3][r1]) };   // e^-zo
        float2v cprev = { c[ci], c[ci + 1] };
        float2v Di = Ei + 1.f;
        float2v Df = Ef + 1.f;
        float2v Dg = Eg + 1.f;
        float2v Dig = Di * Dg;
        float2v num = Df * (1.f - Eg) + cprev * Dig;
        float2v den = Df * Dig;
        float2v rr1 = { frcp(den.x), frcp(den.y) };
        float2v cc  = num * rr1;                  // sigma(f)c + sigma(i)tanh(g)
        c[ci] = cc.x; c[ci + 1] = cc.y;
        float2v ccl = { fmaxf(cc.x, -43.668f), fmaxf(cc.y, -43.668f) };
        float2v carg = ccl * (-2.f * LOG2E);
        float2v Ec = { fexp2(carg.x), fexp2(carg.y) };                   // e^-2c
        float2v d2 = (Eo + 1.f) * (Ec + 1.f);
        float2v rr2 = { frcp(d2.x), frcp(d2.y) };
        float2v hh = (1.f - Ec) * rr2;
        h_lds[1 - pb][(Mt * 16 + quad * 4 + r0) * 136 + kw + l16] = (_Float16)hh.x;
        h_lds[1 - pb][(Mt * 16 + quad * 4 + r1) * 136 + kw + l16] = (_Float16)hh.y;
      }
    }
    __syncthreads();
  }

  // final h_192 is in buffer 0 (192 even). Store fp16 q/k.
  _Float16* dst = (isq ? q_buf : k_buf) + (size_t)head * NSEQ * DM;
  for (int idx = tid; idx < 64 * DM; idx += 512) {
    const int nl = idx >> 7, kk = idx & 127;
    const int n = n0 + nl;
    if (n < NSEQ) dst[(size_t)n * DM + kk] = h_lds[0][nl * 136 + kk];
  }
}

// ---------------------------------------------------------------------------
// Kernel 3: attention for one (head, batch, 32-row s-tile).
// ---------------------------------------------------------------------------
__global__ void attn_kernel(const float* __restrict__ graph,
                            const _Float16* __restrict__ q_buf,
                            const _Float16* __restrict__ k_buf,
                            const float* __restrict__ v_buf,
                            float* __restrict__ out) {
  __shared__ float scores_lds[32 * 337];   // [srow][t], t padded to 337
  __shared__ float v_lds[16 * 196];        // [t_local][l], stride 196

  const int bid = blockIdx.x;
  const int h  = bid / (BATCH * 11);
  const int rem = bid % (BATCH * 11);
  const int b  = rem / 11;
  const int st = rem % 11;
  const int s0 = st * 32;

  const int tid  = threadIdx.x;
  const int w    = tid >> 6;      // wave 0..3
  const int lane = tid & 63;
  const int l16  = lane & 15;
  const int quad = lane >> 4;

  // --- A fragments: q rows (fp16) ---
  half8 aq[2][4];
#pragma unroll
  for (int Mt = 0; Mt < 2; ++Mt) {
    int sg = s0 + Mt * 16 + l16; if (sg > SLEN - 1) sg = SLEN - 1;
    const _Float16* qrow = q_buf + ((size_t)h * NSEQ + (size_t)b * SLEN + sg) * DM;
#pragma unroll
    for (int kc = 0; kc < 4; ++kc)
      aq[Mt][kc] = *(const half8*)&qrow[kc * 32 + quad * 8];
  }

  // --- Phase A: 21 t-tiles of 16, round-robin over 4 waves ---
  for (int tt = w; tt < 21; tt += 4) {
    const int T0t = tt * 16;
    int tgc = T0t + l16; if (tgc > SLEN - 1) tgc = SLEN - 1;
    const _Float16* krow = k_buf + ((size_t)h * NSEQ + (size_t)b * SLEN + tgc) * DM;
    half8 bf[4];
#pragma unroll
    for (int kc = 0; kc < 4; ++kc)
      bf[kc] = *(const half8*)&krow[kc * 32 + quad * 8];
    floatx4 sacc0 = {0.f, 0.f, 0.f, 0.f};
    floatx4 sacc1 = {0.f, 0.f, 0.f, 0.f};
#pragma unroll
    for (int kc = 0; kc < 4; ++kc) {
      sacc0 = __builtin_amdgcn_mfma_f32_16x16x32_f16(aq[0][kc], bf[kc], sacc0, 0, 0, 0);
      sacc1 = __builtin_amdgcn_mfma_f32_16x16x32_f16(aq[1][kc], bf[kc], sacc1, 0, 0, 0);
    }
#pragma unroll
    for (int Mt = 0; Mt < 2; ++Mt) {
#pragma unroll
      for (int r = 0; r < 4; ++r) {
        const int srow = Mt * 16 + quad * 4 + r;
        const int tcol = T0t + l16;
        float sc = (Mt == 0 ? sacc0[r] : sacc1[r]) * 0.088388347648318447f;
        float lk = (sc >= 0.f) ? sc : 0.2f * sc;
        const int sg = s0 + srow;
        if (tcol < SLEN && sg < SLEN) {
          float gv = graph[(size_t)tcol * SLEN + sg];      // graph.T
          if (!(gv != 0.f || tcol == sg)) lk += -1000000000.0f;
        }
        scores_lds[srow * 337 + tcol] = lk;
      }
    }
  }
  __syncthreads();

  // --- softmax: 8 threads per row ---
  {
    const int r = tid >> 3, sub = tid & 7;
    float m = -3.0e38f;
    for (int t = sub; t < SLEN; t += 8) m = fmaxf(m, scores_lds[r * 337 + t]);
#pragma unroll
    for (int o = 1; o < 8; o <<= 1) m = fmaxf(m, __shfl_xor(m, o));
    float ssum = 0.f;
    for (int t = sub; t < SLEN; t += 8) {
      float e = fexp2((scores_lds[r * 337 + t] - m) * LOG2E);
      scores_lds[r * 337 + t] = e;
      ssum += e;
    }
#pragma unroll
    for (int o = 1; o < 8; o <<= 1) ssum += __shfl_xor(ssum, o);
    float inv = frcp(ssum);
    for (int t = sub; t < SLEN; t += 8) scores_lds[r * 337 + t] *= inv;
  }
  __syncthreads();

  // --- Phase B: out[s][l] = sum_t p[s][t] * v[t][l] ---
  const int s_l = tid & 31;
  const int lg  = tid >> 5;                 // 0..7 -> l block of 24
  float oacc[24];
#pragma unroll
  for (int j = 0; j < 24; ++j) oacc[j] = 0.f;

  for (int T0 = 0; T0 < SLEN; T0 += 16) {
    __syncthreads();
    for (int idx = tid; idx < 16 * LSTEPS; idx += 256) {
      int tl = idx & 15, lx = idx >> 4;
      int t = T0 + tl;
      v_lds[tl * 196 + lx] = (t < SLEN)
        ? v_buf[(size_t)h * LSTEPS * NSEQ + (size_t)lx * NSEQ + (size_t)b * SLEN + t]
        : 0.f;
    }
    __syncthreads();
    const int tmax = (SLEN - T0 < 16) ? (SLEN - T0) : 16;
    for (int tl = 0; tl < tmax; ++tl) {
      float p = scores_lds[s_l * 337 + T0 + tl];
      const float* vr = &v_lds[tl * 196 + lg * 24];
#pragma unroll
      for (int j4 = 0; j4 < 6; ++j4) {
        float4 vv = *(const float4*)&vr[j4 * 4];
        oacc[j4 * 4 + 0] = fmaf(p, vv.x, oacc[j4 * 4 + 0]);
        oacc[j4 * 4 + 1] = fmaf(p, vv.y, oacc[j4 * 4 + 1]);
        oacc[j4 * 4 + 2] = fmaf(p, vv.z, oacc[j4 * 4 + 2]);
        oacc[j4 * 4 + 3] = fmaf(p, vv.w, oacc[j4 * 4 + 3]);
      }
    }
  }

  // --- epilogue: leaky + store [B][S][L][H] as fp32 ---
  const int sg = s0 + s_l;
  if (sg < SLEN) {
    size_t base = (((size_t)b * SLEN + sg) * LSTEPS + lg * 24) * HEADS + h;
#pragma unroll
    for (int j = 0; j < 24; ++j) {
      float v = oacc[j];
      v = (v >= 0.f) ? v : 0.2f * v;
      out[base + (size_t)j * HEADS] = v;
    }
  }
}

// ---------------------------------------------------------------------------
extern "C" void kernel_launch(void* const* d_in, const int* in_sizes, int n_in,
                              void* d_out, int out_size, void* d_ws, size_t ws_size,
                              hipStream_t stream) {
  const float* x     = (const float*)d_in[0];
  const float* graph = (const float*)d_in[1];
  const float* qWih  = (const float*)d_in[2];
  const float* qWhh  = (const float*)d_in[3];
  const float* qbih  = (const float*)d_in[4];
  const float* qbhh  = (const float*)d_in[5];
  const float* kWih  = (const float*)d_in[6];
  const float* kWhh  = (const float*)d_in[7];
  const float* kbih  = (const float*)d_in[8];
  const float* kbhh  = (const float*)d_in[9];
  const float* vWih  = (const float*)d_in[10];
  const float* vWhh  = (const float*)d_in[11];
  const float* vbih  = (const float*)d_in[12];
  const float* vbhh  = (const float*)d_in[13];

  // workspace layout
  const size_t v_bytes = (size_t)HEADS * LSTEPS * NSEQ * sizeof(float);   // 63,897,600
  const size_t qk_bytes = (size_t)HEADS * NSEQ * DM * sizeof(_Float16);   // 21,299,200
  float*    v_buf = (float*)d_ws;
  _Float16* q_buf = (_Float16*)((char*)d_ws + v_bytes);
  _Float16* k_buf = (_Float16*)((char*)d_ws + v_bytes + qk_bytes);
  float* out = (float*)d_out;

  v_lstm_kernel<<<dim3((HEADS * NSEQ + 255) / 256), dim3(256), 0, stream>>>(
      x, vWih, vWhh, vbih, vbhh, v_buf);

  qk_lstm_kernel<<<dim3(16 * 163), dim3(512), 0, stream>>>(
      qWih, qWhh, qbih, qbhh, kWih, kWhh, kbih, kbhh, x, q_buf, k_buf);

  attn_kernel<<<dim3(HEADS * BATCH * 11), dim3(256), 0, stream>>>(
      graph, q_buf, k_buf, v_buf, out);
}